// Round 9
// baseline (3975.223 us; speedup 1.0000x reference)
//
#include <hip/hip_runtime.h>
#include <hip/hip_bf16.h>
#include <math.h>

typedef unsigned short u16;

#define DEV static __device__ __forceinline__

DEV float bfu(u16 u) { union { unsigned int i; float f; } v; v.i = ((unsigned int)u) << 16; return v.f; }
DEV u16 fbu(float f) { __hip_bfloat16 h = __float2bfloat16(f); return *reinterpret_cast<u16*>(&h); }

template <typename T> struct ModeOf;
template <> struct ModeOf<u16>   { static constexpr int v = 0; };
template <> struct ModeOf<float> { static constexpr int v = 1; };
template <typename T> DEV float ld(const void* p, size_t i);
template <> DEV float ld<u16>(const void* p, size_t i)   { return bfu(((const u16*)p)[i]); }
template <> DEV float ld<float>(const void* p, size_t i) { return ((const float*)p)[i]; }

// 8-element dot product vs f32 attn row (16B-vectorized input loads), f32 storage
DEV float dot8f(const float* img, size_t idx, const float* ar, int s) {
    const float4 x0 = *reinterpret_cast<const float4*>(img + idx + s);
    const float4 x1 = *reinterpret_cast<const float4*>(img + idx + s + 4);
    const float4 a0 = *reinterpret_cast<const float4*>(ar + s);
    const float4 a1 = *reinterpret_cast<const float4*>(ar + s + 4);
    return a0.x*x0.x + a0.y*x0.y + a0.z*x0.z + a0.w*x0.w
         + a1.x*x1.x + a1.y*x1.y + a1.z*x1.z + a1.w*x1.w;
}

// problem constants
#define NB 4
#define NC 320
#define ND 16
#define NH 32
#define NW 32
#define NS 16384          // 1<<14
#define NHD 40
#define NQD 1280
#define NR 32
#define NTOK 4
#define OUT_N (NB*NC*NS)
#define EPSV 1e-5f
#define SCALE 0.15811388300841898f

// f32-mode y K-split
#define YKS 8
#define YCH (NS / YKS)
// bf16-mode MFMA y K-split
#define YKC 32
#define YCS (NS / YKC)    // 512

// conv geometry (no LDS: B-frags stream from L2)
#define CSL 32
#define NSL 10
#define PACKN (27*10*20*64*8)

typedef __attribute__((ext_vector_type(8))) short bf16x8;
typedef __attribute__((ext_vector_type(4))) float f32x4;

// ---------- reduction helpers ----------
DEV float blk_sum(float v, float* red) {
    __syncthreads();
#pragma unroll
    for (int o = 32; o > 0; o >>= 1) v += __shfl_down(v, o, 64);
    int wv = threadIdx.x >> 6, ln = threadIdx.x & 63;
    if (ln == 0) red[wv] = v;
    __syncthreads();
    return red[0] + red[1] + red[2] + red[3];
}
DEV float blk_max(float v, float* red) {
    __syncthreads();
#pragma unroll
    for (int o = 32; o > 0; o >>= 1) v = fmaxf(v, __shfl_down(v, o, 64));
    int wv = threadIdx.x >> 6, ln = threadIdx.x & 63;
    if (ln == 0) red[wv] = v;
    __syncthreads();
    return fmaxf(fmaxf(red[0], red[1]), fmaxf(red[2], red[3]));
}

// ---------- 0. dtype detect + zero scratch ----------
__global__ void detect_kernel(const u16* __restrict__ lnqw, int* __restrict__ flag,
                              float* __restrict__ zbuf) {
    if (threadIdx.x == 0) flag[0] = (lnqw[0] == 0x3F80) ? 0 : 1;
    if (threadIdx.x < 16) zbuf[threadIdx.x] = 0.f;
}

// ---------- 1. q = LN(cli @ Wq^T + bq) ----------
template <typename T>
__global__ __launch_bounds__(256) void q_kernel(const int* __restrict__ flag,
        const void* __restrict__ cli, const void* __restrict__ Wq, const void* __restrict__ bq,
        const void* __restrict__ lnw, const void* __restrict__ lnb, float* __restrict__ qout) {
    if (*flag != ModeOf<T>::v) return;
    int b = blockIdx.x, tid = threadIdx.x;
    __shared__ float cl[NC];
    __shared__ float red[8];
    for (int i = tid; i < NC; i += 256) cl[i] = ld<T>(cli, b * NC + i);
    __syncthreads();
    float loc[5];
    float s1 = 0.f, s2 = 0.f;
#pragma unroll
    for (int k = 0; k < 5; ++k) {
        int j = tid + k * 256;
        float a = ld<T>(bq, j);
        size_t wr = (size_t)j * NC;
        for (int c = 0; c < NC; ++c) a += cl[c] * ld<T>(Wq, wr + c);
        loc[k] = a; s1 += a; s2 += a * a;
    }
    s1 = blk_sum(s1, red);
    s2 = blk_sum(s2, red);
    float mu = s1 / (float)NQD;
    float var = fmaxf(s2 / (float)NQD - mu * mu, 0.f);
    float rs = rsqrtf(var + EPSV);
#pragma unroll
    for (int k = 0; k < 5; ++k) {
        int j = tid + k * 256;
        qout[(size_t)b * NQD + j] = (loc[k] - mu) * rs * ld<T>(lnw, j) + ld<T>(lnb, j);
    }
}

// ---------- 2. qW + qb (+ bf16 A-fragments for scores MFMA) ----------
template <typename T>
__global__ __launch_bounds__(256) void qw_kernel(const int* __restrict__ flag,
        const float* __restrict__ q, const void* __restrict__ Wk, const void* __restrict__ bk,
        float* __restrict__ qW, float* __restrict__ qb, u16* __restrict__ qwb) {
    if (*flag != ModeOf<T>::v) return;
    int gid = blockIdx.x * 256 + threadIdx.x;
    if (gid < NB * NR * NC) {
        int c = gid % NC;
        int r = (gid / NC) % NR;
        int b = gid / (NC * NR);
        int h = r >> 2, t = r & 3;
        float a = 0.f;
        const float* qb_ = q + (size_t)b * NQD;
        for (int d = 0; d < NHD; ++d)
            a += qb_[(h * NHD + d) * NTOK + t] * ld<T>(Wk, (size_t)(h * NHD + d) * NC + c);
        qW[gid] = a;
        int kk = c >> 5, gg = (c >> 3) & 3, j = c & 7;
        int mf = r >> 4, lane = (gg << 4) | (r & 15);
        qwb[(((size_t)(b * 10 + kk) * 2 + mf) << 9) + (lane << 3) + j] = fbu(a);
    }
    if (gid < NB * NR) {
        int r = gid & 31, b = gid >> 5;
        int h = r >> 2, t = r & 3;
        float a = 0.f;
        const float* qb_ = q + (size_t)b * NQD;
        for (int d = 0; d < NHD; ++d)
            a += qb_[(h * NHD + d) * NTOK + t] * ld<T>(bk, h * NHD + d);
        qb[gid] = a;
    }
}

// ---------- 3. MFMA scores ----------
__global__ __launch_bounds__(256) void scores_mm_kernel(
        const u16* __restrict__ imgt, const u16* __restrict__ qwb,
        const float* __restrict__ qb, float* __restrict__ attn) {
    int b = blockIdx.y;
    int s0 = blockIdx.x * 256 + (threadIdx.x >> 6) * 64;
    int ln = threadIdx.x & 63;
    int col = ln & 15, g = ln >> 4;
    bf16x8 af[10][2];
    const u16* qa = qwb + (size_t)b * 10 * 2 * 512;
#pragma unroll
    for (int kk = 0; kk < 10; ++kk)
#pragma unroll
        for (int mf = 0; mf < 2; ++mf)
            af[kk][mf] = *reinterpret_cast<const bf16x8*>(qa + (((kk << 1) + mf) << 9) + (ln << 3));
    f32x4 acc[2][4];
#pragma unroll
    for (int mf = 0; mf < 2; ++mf)
#pragma unroll
        for (int nf = 0; nf < 4; ++nf) acc[mf][nf] = (f32x4){0.f, 0.f, 0.f, 0.f};
    const u16* xb = imgt + (size_t)b * NS * NC;
#pragma unroll
    for (int kk = 0; kk < 10; ++kk) {
#pragma unroll
        for (int nf = 0; nf < 4; ++nf) {
            bf16x8 bf = *reinterpret_cast<const bf16x8*>(
                xb + (size_t)(s0 + nf * 16 + col) * NC + kk * 32 + (g << 3));
#pragma unroll
            for (int mf = 0; mf < 2; ++mf)
                acc[mf][nf] = __builtin_amdgcn_mfma_f32_16x16x32_bf16(
                    af[kk][mf], bf, acc[mf][nf], 0, 0, 0);
        }
    }
#pragma unroll
    for (int mf = 0; mf < 2; ++mf)
#pragma unroll
        for (int nf = 0; nf < 4; ++nf)
#pragma unroll
            for (int r = 0; r < 4; ++r) {
                int row = mf * 16 + g * 4 + r;
                attn[((size_t)(b * NR + row) << 14) + s0 + nf * 16 + col] =
                    (acc[mf][nf][r] + qb[b * NR + row]) * SCALE;
            }
}

// ---------- 4a. softmax partial ----------
__global__ __launch_bounds__(256) void smax_part_kernel(const float* __restrict__ attn,
        float* __restrict__ pm, float* __restrict__ pl) {
    int row = blockIdx.x, kc = blockIdx.y;
    const float* rp = attn + ((size_t)row << 14) + kc * 2048;
    __shared__ float red[8];
    int t4 = threadIdx.x * 4;
    float4 v0 = *reinterpret_cast<const float4*>(rp + t4);
    float4 v1 = *reinterpret_cast<const float4*>(rp + t4 + 1024);
    float m = fmaxf(fmaxf(fmaxf(v0.x, v0.y), fmaxf(v0.z, v0.w)),
                    fmaxf(fmaxf(v1.x, v1.y), fmaxf(v1.z, v1.w)));
    m = blk_max(m, red);
    float s = expf(v0.x - m) + expf(v0.y - m) + expf(v0.z - m) + expf(v0.w - m)
            + expf(v1.x - m) + expf(v1.y - m) + expf(v1.z - m) + expf(v1.w - m);
    s = blk_sum(s, red);
    if (threadIdx.x == 0) { pm[row * 8 + kc] = m; pl[row * 8 + kc] = s; }
}

// ---------- 4b. combine chunk stats ----------
__global__ __launch_bounds__(128) void smax_comb_kernel(const float* __restrict__ pm,
        const float* __restrict__ pl, float* __restrict__ gm, float* __restrict__ gli) {
    int row = threadIdx.x;
    float M = -1e30f;
#pragma unroll
    for (int k = 0; k < 8; ++k) M = fmaxf(M, pm[row * 8 + k]);
    float L = 0.f;
#pragma unroll
    for (int k = 0; k < 8; ++k) L += pl[row * 8 + k] * expf(pm[row * 8 + k] - M);
    gm[row] = M; gli[row] = 1.f / L;
}

// ---------- 4c. softmax finalize: f32 + bf16 copies ----------
__global__ __launch_bounds__(256) void smax_fin_kernel(float* __restrict__ attn,
        const float* __restrict__ gm, const float* __restrict__ gli, u16* __restrict__ attnb) {
    int row = blockIdx.x, kc = blockIdx.y;
    size_t base = ((size_t)row << 14) + kc * 2048;
    float M = gm[row], LI = gli[row];
    int t4 = threadIdx.x * 4;
#pragma unroll
    for (int h = 0; h < 2; ++h) {
        size_t i = base + t4 + h * 1024;
        float4 v = *reinterpret_cast<const float4*>(attn + i);
        v.x = expf(v.x - M) * LI; v.y = expf(v.y - M) * LI;
        v.z = expf(v.z - M) * LI; v.w = expf(v.w - M) * LI;
        *reinterpret_cast<float4*>(attn + i) = v;
        ushort4 bv; bv.x = fbu(v.x); bv.y = fbu(v.y); bv.z = fbu(v.z); bv.w = fbu(v.w);
        *reinterpret_cast<ushort4*>(attnb + i) = bv;
    }
}

// ---------- 5A (bf16 mode). MFMA y ----------
__global__ __launch_bounds__(256) void ymm_kernel(const int* __restrict__ flag,
        const u16* __restrict__ attnb, const void* __restrict__ img, float* __restrict__ yp) {
    if (*flag != 0) return;
    int kc = blockIdx.x, ct = blockIdx.y, b = blockIdx.z;
    int wv = threadIdx.x >> 6, ln = threadIdx.x & 63;
    int col = ln & 15, g = ln >> 4;
    int s0 = kc * YCS;
    const u16* imgB = (const u16*)img;
    const u16* ap0 = attnb + (((size_t)b * 32 + col) << 14) + s0 + (g << 3);
    const u16* bp  = imgB + (((size_t)(b * NC + ct * 64 + wv * 16 + col)) << 14) + s0 + (g << 3);
    f32x4 acc[2];
    acc[0] = (f32x4){0.f, 0.f, 0.f, 0.f};
    acc[1] = (f32x4){0.f, 0.f, 0.f, 0.f};
#pragma unroll
    for (int ks = 0; ks < YCS / 32; ++ks) {
        bf16x8 bf = *reinterpret_cast<const bf16x8*>(bp + ks * 32);
        bf16x8 a0 = *reinterpret_cast<const bf16x8*>(ap0 + ks * 32);
        bf16x8 a1 = *reinterpret_cast<const bf16x8*>(ap0 + (16 << 14) + ks * 32);
        acc[0] = __builtin_amdgcn_mfma_f32_16x16x32_bf16(a0, bf, acc[0], 0, 0, 0);
        acc[1] = __builtin_amdgcn_mfma_f32_16x16x32_bf16(a1, bf, acc[1], 0, 0, 0);
    }
    int c = ct * 64 + wv * 16 + col;
#pragma unroll
    for (int mf = 0; mf < 2; ++mf)
#pragma unroll
        for (int r = 0; r < 4; ++r) {
            int row = b * 32 + mf * 16 + g * 4 + r;
            yp[((size_t)kc * NB * NR + row) * NC + c] = acc[mf][r];
        }
}

// ---------- 5B (f32 mode). VALU y ----------
template <typename T>
__global__ __launch_bounds__(256) void y_kernel(const int* __restrict__ flag,
        const float* __restrict__ attn, const void* __restrict__ img, float* __restrict__ yp) {
    if (*flag != ModeOf<T>::v) return;
    int row = blockIdx.x;
    int ks  = blockIdx.y;
    int b = row >> 5;
    int wv = threadIdx.x >> 6, ln = threadIdx.x & 63;
    const float* ar = attn + ((size_t)row << 14) + ks * YCH;
    size_t xb = (size_t)b * NC * NS + ks * YCH;
    float* yout = yp + ((size_t)ks * NB * NR + row) * NC;
    for (int c = wv; c < NC; c += 4) {
        size_t xr = xb + ((size_t)c << 14);
        float p = 0.f;
#pragma unroll
        for (int it = 0; it < YCH / 512; ++it)
            p += dot8f((const float*)img, xr, ar, it * 512 + ln * 8);
#pragma unroll
        for (int o = 32; o > 0; o >>= 1) p += __shfl_down(p, o, 64);
        if (ln == 0) yout[c] = p;
    }
}

// ---------- 5b. y reduce over K-chunks ----------
__global__ __launch_bounds__(256) void yred_kernel(const int* __restrict__ flag, int mode, int nk,
        const float* __restrict__ yp, float* __restrict__ y) {
    if (*flag != mode) return;
    int i = blockIdx.x * 256 + threadIdx.x;
    if (i >= NB * NR * NC) return;
    float s = 0.f;
    for (int k = 0; k < nk; ++k) s += yp[(size_t)k * NB * NR * NC + i];
    y[i] = s;
}

// ---------- 6. o = Wv-contraction of y; o2 = LN(o @ Wo^T + bo) ----------
template <typename T>
__global__ __launch_bounds__(256) void o_kernel(const int* __restrict__ flag,
        const float* __restrict__ y, const void* __restrict__ Wv, const void* __restrict__ bv,
        const void* __restrict__ Wo, const void* __restrict__ bo,
        const void* __restrict__ lnw, const void* __restrict__ lnb, float* __restrict__ o2) {
    if (*flag != ModeOf<T>::v) return;
    int b = blockIdx.x, tid = threadIdx.x;
    __shared__ float yl[NR * NC];
    __shared__ float ol[NQD];
    __shared__ float red[8];
    for (int i = tid; i < NR * NC; i += 256) yl[i] = y[(size_t)b * NR * NC + i];
    __syncthreads();
#pragma unroll
    for (int k = 0; k < 5; ++k) {
        int i = tid + k * 256;
        int h = i / 160, rem = i - h * 160;
        int d = rem >> 2, t = rem & 3;
        int wr = h * NHD + d, r = h * NTOK + t;
        float a = ld<T>(bv, wr);
        size_t wvr = (size_t)wr * NC;
        const float* yr = yl + r * NC;
        for (int c = 0; c < NC; ++c) a += ld<T>(Wv, wvr + c) * yr[c];
        ol[i] = a;
    }
    __syncthreads();
    for (int j = tid; j < NC; j += 256) {
        float a = ld<T>(bo, j);
        size_t wor = (size_t)j * NQD;
        for (int i = 0; i < NQD; ++i) a += ld<T>(Wo, wor + i) * ol[i];
        yl[j] = a;
    }
    __syncthreads();
    float s1 = 0.f, s2 = 0.f;
    for (int j = tid; j < NC; j += 256) { float v = yl[j]; s1 += v; s2 += v * v; }
    s1 = blk_sum(s1, red);
    s2 = blk_sum(s2, red);
    float mu = s1 / (float)NC;
    float var = fmaxf(s2 / (float)NC - mu * mu, 0.f);
    float rs = rsqrtf(var + EPSV);
    for (int j = tid; j < NC; j += 256)
        o2[(size_t)b * NC + j] = (yl[j] - mu) * rs * ld<T>(lnw, j) + ld<T>(lnb, j);
}

// ---------- 7. P broadcast taps ----------
template <typename T>
__global__ __launch_bounds__(256) void p_kernel(const int* __restrict__ flag,
        const float* __restrict__ o2, const void* __restrict__ Wf1, float* __restrict__ P) {
    if (*flag != ModeOf<T>::v) return;
    int o = blockIdx.x, b = blockIdx.y;
    int tid = threadIdx.x, wv = tid >> 6, ln = tid & 63;
    __shared__ float red[4 * 27];
    __shared__ float taps[27];
    float acc[27];
#pragma unroll
    for (int k = 0; k < 27; ++k) acc[k] = 0.f;
    for (int c = tid; c < NC; c += 256) {
        float oc = o2[(size_t)b * NC + c];
        size_t wp = ((size_t)o * 640 + 320 + c) * 27;
#pragma unroll
        for (int k = 0; k < 27; ++k) acc[k] += oc * ld<T>(Wf1, wp + k);
    }
#pragma unroll
    for (int k = 0; k < 27; ++k) {
        float v = acc[k];
#pragma unroll
        for (int off = 32; off > 0; off >>= 1) v += __shfl_down(v, off, 64);
        if (ln == 0) red[wv * 27 + k] = v;
    }
    __syncthreads();
    if (tid < 27) taps[tid] = red[tid] + red[27 + tid] + red[54 + tid] + red[81 + tid];
    __syncthreads();
    if (tid < 27) {
        int pd = tid / 9, ph = (tid / 3) % 3, pw = tid % 3;
        float s = 0.f;
        for (int kd = 0; kd < 3; ++kd) {
            if ((pd == 0 && kd == 0) || (pd == 2 && kd == 2)) continue;
            for (int kh = 0; kh < 3; ++kh) {
                if ((ph == 0 && kh == 0) || (ph == 2 && kh == 2)) continue;
                for (int kw = 0; kw < 3; ++kw) {
                    if ((pw == 0 && kw == 0) || (pw == 2 && kw == 2)) continue;
                    s += taps[kd * 9 + kh * 3 + kw];
                }
            }
        }
        P[(size_t)(b * NC + o) * 27 + tid] = s;
    }
}

// ---------- 8a. channel-last transpose ----------
template <typename T>
__global__ __launch_bounds__(256) void imgt_kernel(const int* __restrict__ flag,
        const void* __restrict__ img, u16* __restrict__ outT) {
    if (*flag != ModeOf<T>::v) return;
    int b = blockIdx.z, c0 = blockIdx.y << 5, s0 = blockIdx.x << 5;
    int r = threadIdx.x >> 3, c4 = (threadIdx.x & 7) << 2;
    __shared__ float tile[32][33];
#pragma unroll
    for (int j = 0; j < 4; ++j)
        tile[r][c4 + j] = ld<T>(img, ((size_t)(b * NC + c0 + r) << 14) + s0 + c4 + j);
    __syncthreads();
    u16* op = outT + ((size_t)b * NS + s0 + r) * NC + c0 + c4;
#pragma unroll
    for (int j = 0; j < 4; ++j) op[j] = fbu(tile[c4 + j][r]);
}

// ---------- 8b. weight pre-pack ----------
template <typename TW>
__global__ __launch_bounds__(256) void pack_kernel(const int* __restrict__ flag,
        const void* __restrict__ wgt, const void* __restrict__ bias,
        u16* __restrict__ wpack, float* __restrict__ biasf, int wic) {
    if (*flag != ModeOf<TW>::v) return;
    int gid = blockIdx.x * 256 + threadIdx.x;
    if (gid < NC) biasf[gid] = ld<TW>(bias, gid);
    int lane = gid & 63;
    int rest = gid >> 6;
    int obg = rest % 20;  rest /= 20;
    int t = rest % 27;    int cs = rest / 27;
    int o  = (obg << 4) + (lane & 15);
    int c0 = (cs << 5) + ((lane >> 4) << 3);
    u16* dst = wpack + (size_t)gid * 8;
#pragma unroll
    for (int j = 0; j < 8; ++j)
        dst[j] = fbu(ld<TW>(wgt, ((size_t)o * wic + c0 + j) * 27 + t));
}

// ---------- 8c. MFMA implicit-GEMM conv, NO LDS: B-frags stream from L2 ----------
// inT: [b][s][320] bf16 channel-last. Block: M=64 o's x N=256 spatial (2d x 4h x 32w).
// 4 waves x (4 M-frags x 4 N-frags). Per tap each lane loads its 16B B-frag directly
// from global (boundary lanes read a zeros buffer). No barriers anywhere in the K-loop:
// pure dataflow, latency hidden by 16 waves/CU of TLP + compiler pipelining.
__global__ __launch_bounds__(256, 4) void convmm_kernel(
        const u16* __restrict__ inT, const u16* __restrict__ wpack,
        const float* __restrict__ biasf, const float* __restrict__ Pp,
        const u16* __restrict__ zbuf, u16* __restrict__ out) {
    int d0 = (blockIdx.x >> 3) << 1;   // 8 d-tiles of 2
    int h0 = (blockIdx.x & 7) << 2;    // 8 h-tiles of 4
    int ob = blockIdx.y;               // o-tile (64 o's)
    int b  = blockIdx.z;
    int tid = threadIdx.x;
    int wv = tid >> 6, ln = tid & 63;
    int col = ln & 15, g = ln >> 4;

    f32x4 acc[4][4];
#pragma unroll
    for (int mi = 0; mi < 4; ++mi)
#pragma unroll
        for (int ni = 0; ni < 4; ++ni) acc[mi][ni] = (f32x4){0.f, 0.f, 0.f, 0.f};

    // per-N-frag output coordinates and base pointers (tap offset added as constant)
    int dA[4], hA[4], wA[4];
    const u16* bpA[4];
#pragma unroll
    for (int ni = 0; ni < 4; ++ni) {
        int nb = (wv << 2) + ni;
        int r2 = nb >> 1;
        dA[ni] = d0 + (r2 >> 2);
        hA[ni] = h0 + (r2 & 3);
        wA[ni] = ((nb & 1) << 4) + col;
        int px = (dA[ni] << 10) + (hA[ni] << 5) + wA[ni];
        bpA[ni] = inT + (size_t)b * NS * NC + (size_t)px * NC + (g << 3);
    }

    for (int cs = 0; cs < NSL; ++cs) {
        const u16* wp = wpack + (size_t)cs * 27 * 20 * 512;
        int cof = cs << 5;    // channel offset within row
#pragma unroll
        for (int t = 0; t < 27; ++t) {
            const int kd = t / 9, kh = (t / 3) % 3, kw = t % 3;
            const int tap = (kd - 1) * 1024 + (kh - 1) * 32 + (kw - 1);  // pixel delta
            bf16x8 af[4];
#pragma unroll
            for (int mi = 0; mi < 4; ++mi)
                af[mi] = *reinterpret_cast<const bf16x8*>(
                    wp + ((size_t)(t * 20 + (ob << 2) + mi) << 9) + (ln << 3));
            bf16x8 bfr[4];
#pragma unroll
            for (int ni = 0; ni < 4; ++ni) {
                bool ok = ((unsigned)(dA[ni] + kd - 1) < ND) &&
                          ((unsigned)(hA[ni] + kh - 1) < NH) &&
                          ((unsigned)(wA[ni] + kw - 1) < NW);
                const u16* src = ok ? (bpA[ni] + (ptrdiff_t)tap * NC + cof) : zbuf;
                bfr[ni] = *reinterpret_cast<const bf16x8*>(src);
            }
#pragma unroll
            for (int mi = 0; mi < 4; ++mi)
#pragma unroll
                for (int ni = 0; ni < 4; ++ni)
                    acc[mi][ni] = __builtin_amdgcn_mfma_f32_16x16x32_bf16(
                        af[mi], bfr[ni], acc[mi][ni], 0, 0, 0);
        }
    }

    // epilogue: + bias (+ P broadcast term for conv1), bf16 store [b][o][s]
#pragma unroll
    for (int ni = 0; ni < 4; ++ni) {
        int d = dA[ni], h = hA[ni], w = wA[ni];
        int pd = (d == 0) ? 0 : ((d == ND - 1) ? 2 : 1);
        int ph = (h == 0) ? 0 : ((h == NH - 1) ? 2 : 1);
        int pw = (w == 0) ? 0 : ((w == NW - 1) ? 2 : 1);
        size_t sidx = ((size_t)d << 10) + (h << 5) + w;
#pragma unroll
        for (int mi = 0; mi < 4; ++mi) {
#pragma unroll
            for (int r = 0; r < 4; ++r) {
                int o = (ob << 6) + (mi << 4) + (g << 2) + r;
                float v = acc[mi][ni][r] + biasf[o];
                if (Pp) v += Pp[(size_t)(b * NC + o) * 27 + pd * 9 + ph * 3 + pw];
                out[((size_t)(b * NC + o) << 14) + sidx] = fbu(v);
            }
        }
    }
}

// ---------- 9. per-(b,o) mean / rstd over S (bf16 input, 16B loads) ----------
__global__ __launch_bounds__(256) void stats_kernel(const u16* __restrict__ raw, float* __restrict__ mean,
                                                    float* __restrict__ rstd) {
    int bo = blockIdx.x;
    const u16* base = raw + ((size_t)bo << 14);
    __shared__ float red[8];
    float s1 = 0.f, s2 = 0.f;
    for (int s0 = threadIdx.x * 8; s0 < NS; s0 += 2048) {
        uint4 v = *reinterpret_cast<const uint4*>(base + s0);
        float x0 = bfu(v.x & 0xffff), x1 = bfu(v.x >> 16);
        float x2 = bfu(v.y & 0xffff), x3 = bfu(v.y >> 16);
        float x4 = bfu(v.z & 0xffff), x5 = bfu(v.z >> 16);
        float x6 = bfu(v.w & 0xffff), x7 = bfu(v.w >> 16);
        s1 += ((x0 + x1) + (x2 + x3)) + ((x4 + x5) + (x6 + x7));
        s2 += ((x0*x0 + x1*x1) + (x2*x2 + x3*x3)) + ((x4*x4 + x5*x5) + (x6*x6 + x7*x7));
    }
    s1 = blk_sum(s1, red);
    s2 = blk_sum(s2, red);
    if (threadIdx.x == 0) {
        float mu = s1 / (float)NS;
        float var = fmaxf(s2 / (float)NS - mu * mu, 0.f);
        mean[bo] = mu;
        rstd[bo] = rsqrtf(var + EPSV);
    }
}

// ---------- 10. h1 = gelu(instnorm(raw1)) -> channel-last bf16 ----------
__global__ __launch_bounds__(256) void norm1t_kernel(const u16* __restrict__ raw,
        const float* __restrict__ mean, const float* __restrict__ rstd, u16* __restrict__ h1t) {
    int b = blockIdx.z, c0 = blockIdx.y << 5, s0 = blockIdx.x << 5;
    int r = threadIdx.x >> 3, c4 = (threadIdx.x & 7) << 2;
    __shared__ float tile[32][33];
    int bo = b * NC + c0 + r;
    float mu = mean[bo], rs = rstd[bo];
    const u16* rp = raw + ((size_t)bo << 14) + s0 + c4;
#pragma unroll
    for (int j = 0; j < 4; ++j) {
        float xn = (bfu(rp[j]) - mu) * rs;
        tile[r][c4 + j] = 0.5f * xn * (1.f + erff(xn * 0.70710678118654752f));
    }
    __syncthreads();
    u16* op = h1t + ((size_t)b * NS + s0 + r) * NC + c0 + c4;
#pragma unroll
    for (int j = 0; j < 4; ++j) op[j] = fbu(tile[c4 + j][r]);
}

// ---------- 11. out = instnorm(raw2) + img, 4 elems/thread ----------
template <typename T>
__global__ __launch_bounds__(256) void final_kernel(const int* __restrict__ flag,
        const u16* __restrict__ raw, const float* __restrict__ mean, const float* __restrict__ rstd,
        const void* __restrict__ img, void* __restrict__ outp) {
    if (*flag != ModeOf<T>::v) return;
    int idx = (blockIdx.x * 256 + threadIdx.x) * 4;
    if (idx >= OUT_N) return;
    int bo = idx >> 14;
    float mu = mean[bo], rs = rstd[bo];
    ushort4 rv = *reinterpret_cast<const ushort4*>(raw + idx);
    float r0 = (bfu(rv.x) - mu) * rs;
    float r1 = (bfu(rv.y) - mu) * rs;
    float r2 = (bfu(rv.z) - mu) * rs;
    float r3 = (bfu(rv.w) - mu) * rs;
    if (ModeOf<T>::v == 0) {
        ushort4 iv = *reinterpret_cast<const ushort4*>((const u16*)img + idx);
        ushort4 ov;
        ov.x = fbu(r0 + bfu(iv.x)); ov.y = fbu(r1 + bfu(iv.y));
        ov.z = fbu(r2 + bfu(iv.z)); ov.w = fbu(r3 + bfu(iv.w));
        *reinterpret_cast<ushort4*>((u16*)outp + idx) = ov;
    } else {
        float4 iv = *reinterpret_cast<const float4*>((const float*)img + idx);
        float4 ov = make_float4(r0 + iv.x, r1 + iv.y, r2 + iv.z, r3 + iv.w);
        *reinterpret_cast<float4*>((float*)outp + idx) = ov;
    }
}

extern "C" void kernel_launch(void* const* d_in, const int* in_sizes, int n_in,
                              void* d_out, int out_size, void* d_ws, size_t ws_size,
                              hipStream_t stream) {
    const void* IMG  = d_in[0];
    const void* CLI  = d_in[1];
    const void* WQ   = d_in[2];
    const void* BQ   = d_in[3];
    const void* LNQW = d_in[4];
    const void* LNQB = d_in[5];
    const void* WK   = d_in[6];
    const void* BK   = d_in[7];
    const void* WV   = d_in[8];
    const void* BV   = d_in[9];
    const void* WO   = d_in[10];
    const void* BO   = d_in[11];
    const void* LNOW = d_in[12];
    const void* LNOB = d_in[13];
    const void* WF1  = d_in[14];
    const void* BF1  = d_in[15];
    const void* WF2  = d_in[16];
    const void* BF2  = d_in[17];

    char* ws = (char*)d_ws;
    size_t off = 0;
    auto alloc = [&](size_t bytes) { void* p = ws + off; off += (bytes + 255) & ~(size_t)255; return p; };
    int*   FLAG  = (int*)  alloc(256);
    float* ZBUF  = (float*)alloc(256);
    u16*   RAW   = (u16*)  alloc((size_t)OUT_N * 2);         // 41.9 MB
    float* Qf    = (float*)alloc((size_t)NB * NQD * 4);
    float* QW    = (float*)alloc((size_t)NB * NR * NC * 4);
    float* QB    = (float*)alloc((size_t)NB * NR * 4);
    u16*   QWB   = (u16*)  alloc((size_t)NB * 10 * 2 * 512 * 2);
    float* Yb    = (float*)alloc((size_t)NB * NR * NC * 4);
    float* O2    = (float*)alloc((size_t)NB * NC * 4);
    float* PB    = (float*)alloc((size_t)NB * NC * 27 * 4);
    float* MEAN  = (float*)alloc((size_t)NB * NC * 4);
    float* RSTD  = (float*)alloc((size_t)NB * NC * 4);
    float* PM    = (float*)alloc((size_t)NB * NR * 8 * 4);
    float* PL    = (float*)alloc((size_t)NB * NR * 8 * 4);
    float* GM    = (float*)alloc((size_t)NB * NR * 4);
    float* GLI   = (float*)alloc((size_t)NB * NR * 4);
    u16*   WPACK = (u16*)  alloc((size_t)PACKN * 2);
    float* BIASF = (float*)alloc((size_t)NC * 4);
    // RAW region aliasing (RAW dead until convmm):
    float* YP    = (float*)RAW;                              // up to 5.25 MB (32 chunks)
    float* ATTN  = (float*)((char*)RAW + (16u << 20));       // 8.39 MB f32
    u16*   ATTNB = (u16*)  ((char*)RAW + (26u << 20));       // 4.2 MB bf16
    u16*   IMGT  = (u16*)d_out;
    u16*   H1    = (u16*)d_out;
    (void)ws_size; (void)n_in; (void)in_sizes; (void)out_size;

    detect_kernel<<<1, 64, 0, stream>>>((const u16*)LNQW, FLAG, ZBUF);

    imgt_kernel<u16>  <<<dim3(512, 10, NB), 256, 0, stream>>>(FLAG, IMG, IMGT);
    imgt_kernel<float><<<dim3(512, 10, NB), 256, 0, stream>>>(FLAG, IMG, IMGT);

    q_kernel<u16>  <<<NB, 256, 0, stream>>>(FLAG, CLI, WQ, BQ, LNQW, LNQB, Qf);
    q_kernel<float><<<NB, 256, 0, stream>>>(FLAG, CLI, WQ, BQ, LNQW, LNQB, Qf);

    int qwg = (NB * NR * NC + 255) / 256;
    qw_kernel<u16>  <<<qwg, 256, 0, stream>>>(FLAG, Qf, WK, BK, QW, QB, QWB);
    qw_kernel<float><<<qwg, 256, 0, stream>>>(FLAG, Qf, WK, BK, QW, QB, QWB);

    scores_mm_kernel<<<dim3(64, NB), 256, 0, stream>>>(IMGT, QWB, QB, ATTN);

    smax_part_kernel<<<dim3(NB * NR, 8), 256, 0, stream>>>(ATTN, PM, PL);
    smax_comb_kernel<<<1, 128, 0, stream>>>(PM, PL, GM, GLI);
    smax_fin_kernel<<<dim3(NB * NR, 8), 256, 0, stream>>>(ATTN, GM, GLI, ATTNB);

    ymm_kernel<<<dim3(YKC, 5, NB), 256, 0, stream>>>(FLAG, ATTNB, IMG, YP);
    y_kernel<float><<<dim3(NB * NR, YKS), 256, 0, stream>>>(FLAG, ATTN, IMG, YP);

    int yrg = (NB * NR * NC + 255) / 256;
    yred_kernel<<<yrg, 256, 0, stream>>>(FLAG, 0, YKC, YP, Yb);
    yred_kernel<<<yrg, 256, 0, stream>>>(FLAG, 1, YKS, YP, Yb);

    o_kernel<u16>  <<<NB, 256, 0, stream>>>(FLAG, Yb, WV, BV, WO, BO, LNOW, LNOB, O2);
    o_kernel<float><<<NB, 256, 0, stream>>>(FLAG, Yb, WV, BV, WO, BO, LNOW, LNOB, O2);

    p_kernel<u16>  <<<dim3(NC, NB), 256, 0, stream>>>(FLAG, O2, WF1, PB);
    p_kernel<float><<<dim3(NC, NB), 256, 0, stream>>>(FLAG, O2, WF1, PB);

    int pkg = (PACKN / 8 + 255) / 256;
    pack_kernel<u16>  <<<pkg, 256, 0, stream>>>(FLAG, WF1, BF1, WPACK, BIASF, 640);
    pack_kernel<float><<<pkg, 256, 0, stream>>>(FLAG, WF1, BF1, WPACK, BIASF, 640);

    convmm_kernel<<<dim3(64, 5, NB), 256, 0, stream>>>(IMGT, WPACK, BIASF, PB, (const u16*)ZBUF, RAW);

    stats_kernel<<<NB * NC, 256, 0, stream>>>(RAW, MEAN, RSTD);
    norm1t_kernel<<<dim3(512, 10, NB), 256, 0, stream>>>(RAW, MEAN, RSTD, H1);

    pack_kernel<u16>  <<<pkg, 256, 0, stream>>>(FLAG, WF2, BF2, WPACK, BIASF, 320);
    pack_kernel<float><<<pkg, 256, 0, stream>>>(FLAG, WF2, BF2, WPACK, BIASF, 320);

    convmm_kernel<<<dim3(64, 5, NB), 256, 0, stream>>>(H1, WPACK, BIASF, nullptr, (const u16*)ZBUF, RAW);

    stats_kernel<<<NB * NC, 256, 0, stream>>>(RAW, MEAN, RSTD);

    final_kernel<u16>  <<<(OUT_N / 4 + 255) / 256, 256, 0, stream>>>(FLAG, RAW, MEAN, RSTD, IMG, d_out);
    final_kernel<float><<<(OUT_N / 4 + 255) / 256, 256, 0, stream>>>(FLAG, RAW, MEAN, RSTD, IMG, d_out);
}

// Round 10
// 2038.807 us; speedup vs baseline: 1.9498x; 1.9498x over previous
//
#include <hip/hip_runtime.h>
#include <hip/hip_bf16.h>
#include <math.h>

typedef unsigned short u16;

#define DEV static __device__ __forceinline__

DEV float bfu(u16 u) { union { unsigned int i; float f; } v; v.i = ((unsigned int)u) << 16; return v.f; }
DEV u16 fbu(float f) { __hip_bfloat16 h = __float2bfloat16(f); return *reinterpret_cast<u16*>(&h); }

template <typename T> struct ModeOf;
template <> struct ModeOf<u16>   { static constexpr int v = 0; };
template <> struct ModeOf<float> { static constexpr int v = 1; };
template <typename T> DEV float ld(const void* p, size_t i);
template <> DEV float ld<u16>(const void* p, size_t i)   { return bfu(((const u16*)p)[i]); }
template <> DEV float ld<float>(const void* p, size_t i) { return ((const float*)p)[i]; }

// 8-element dot product vs f32 attn row (16B-vectorized input loads), f32 storage
DEV float dot8f(const float* img, size_t idx, const float* ar, int s) {
    const float4 x0 = *reinterpret_cast<const float4*>(img + idx + s);
    const float4 x1 = *reinterpret_cast<const float4*>(img + idx + s + 4);
    const float4 a0 = *reinterpret_cast<const float4*>(ar + s);
    const float4 a1 = *reinterpret_cast<const float4*>(ar + s + 4);
    return a0.x*x0.x + a0.y*x0.y + a0.z*x0.z + a0.w*x0.w
         + a1.x*x1.x + a1.y*x1.y + a1.z*x1.z + a1.w*x1.w;
}

// problem constants
#define NB 4
#define NC 320
#define ND 16
#define NH 32
#define NW 32
#define NS 16384          // 1<<14
#define NHD 40
#define NQD 1280
#define NR 32
#define NTOK 4
#define OUT_N (NB*NC*NS)
#define EPSV 1e-5f
#define SCALE 0.15811388300841898f

// f32-mode y K-split
#define YKS 8
#define YCH (NS / YKS)
// bf16-mode MFMA y K-split
#define YKC 32
#define YCS (NS / YKC)    // 512

// MFMA conv geometry (round-3 measured optimum)
#define CSL 32
#define NSL 10
#define HALO_D 4
#define HALO_H 6
#define PIXW 34
#define NPIX (HALO_D*HALO_H*PIXW)   // 816 -> 52224 B LDS, 3 blocks/CU
#define PACKN (27*10*20*64*8)

typedef __attribute__((ext_vector_type(8))) short bf16x8;
typedef __attribute__((ext_vector_type(4))) float f32x4;

DEV int swz4(int p) { return (p + (p >> 2)) & 3; }

// ---------- reduction helpers ----------
DEV float blk_sum(float v, float* red) {
    __syncthreads();
#pragma unroll
    for (int o = 32; o > 0; o >>= 1) v += __shfl_down(v, o, 64);
    int wv = threadIdx.x >> 6, ln = threadIdx.x & 63;
    if (ln == 0) red[wv] = v;
    __syncthreads();
    return red[0] + red[1] + red[2] + red[3];
}
DEV float blk_max(float v, float* red) {
    __syncthreads();
#pragma unroll
    for (int o = 32; o > 0; o >>= 1) v = fmaxf(v, __shfl_down(v, o, 64));
    int wv = threadIdx.x >> 6, ln = threadIdx.x & 63;
    if (ln == 0) red[wv] = v;
    __syncthreads();
    return fmaxf(fmaxf(red[0], red[1]), fmaxf(red[2], red[3]));
}

// ---------- 0. dtype detect ----------
__global__ void detect_kernel(const u16* __restrict__ lnqw, int* __restrict__ flag) {
    if (threadIdx.x == 0) flag[0] = (lnqw[0] == 0x3F80) ? 0 : 1;
}

// ---------- 1. q = LN(cli @ Wq^T + bq) ----------
template <typename T>
__global__ __launch_bounds__(256) void q_kernel(const int* __restrict__ flag,
        const void* __restrict__ cli, const void* __restrict__ Wq, const void* __restrict__ bq,
        const void* __restrict__ lnw, const void* __restrict__ lnb, float* __restrict__ qout) {
    if (*flag != ModeOf<T>::v) return;
    int b = blockIdx.x, tid = threadIdx.x;
    __shared__ float cl[NC];
    __shared__ float red[8];
    for (int i = tid; i < NC; i += 256) cl[i] = ld<T>(cli, b * NC + i);
    __syncthreads();
    float loc[5];
    float s1 = 0.f, s2 = 0.f;
#pragma unroll
    for (int k = 0; k < 5; ++k) {
        int j = tid + k * 256;
        float a = ld<T>(bq, j);
        size_t wr = (size_t)j * NC;
        for (int c = 0; c < NC; ++c) a += cl[c] * ld<T>(Wq, wr + c);
        loc[k] = a; s1 += a; s2 += a * a;
    }
    s1 = blk_sum(s1, red);
    s2 = blk_sum(s2, red);
    float mu = s1 / (float)NQD;
    float var = fmaxf(s2 / (float)NQD - mu * mu, 0.f);
    float rs = rsqrtf(var + EPSV);
#pragma unroll
    for (int k = 0; k < 5; ++k) {
        int j = tid + k * 256;
        qout[(size_t)b * NQD + j] = (loc[k] - mu) * rs * ld<T>(lnw, j) + ld<T>(lnb, j);
    }
}

// ---------- 2. qW + qb (+ bf16 A-fragments for scores MFMA) ----------
template <typename T>
__global__ __launch_bounds__(256) void qw_kernel(const int* __restrict__ flag,
        const float* __restrict__ q, const void* __restrict__ Wk, const void* __restrict__ bk,
        float* __restrict__ qW, float* __restrict__ qb, u16* __restrict__ qwb) {
    if (*flag != ModeOf<T>::v) return;
    int gid = blockIdx.x * 256 + threadIdx.x;
    if (gid < NB * NR * NC) {
        int c = gid % NC;
        int r = (gid / NC) % NR;
        int b = gid / (NC * NR);
        int h = r >> 2, t = r & 3;
        float a = 0.f;
        const float* qb_ = q + (size_t)b * NQD;
        for (int d = 0; d < NHD; ++d)
            a += qb_[(h * NHD + d) * NTOK + t] * ld<T>(Wk, (size_t)(h * NHD + d) * NC + c);
        qW[gid] = a;
        int kk = c >> 5, gg = (c >> 3) & 3, j = c & 7;
        int mf = r >> 4, lane = (gg << 4) | (r & 15);
        qwb[(((size_t)(b * 10 + kk) * 2 + mf) << 9) + (lane << 3) + j] = fbu(a);
    }
    if (gid < NB * NR) {
        int r = gid & 31, b = gid >> 5;
        int h = r >> 2, t = r & 3;
        float a = 0.f;
        const float* qb_ = q + (size_t)b * NQD;
        for (int d = 0; d < NHD; ++d)
            a += qb_[(h * NHD + d) * NTOK + t] * ld<T>(bk, h * NHD + d);
        qb[gid] = a;
    }
}

// ---------- 3. MFMA scores ----------
__global__ __launch_bounds__(256) void scores_mm_kernel(
        const u16* __restrict__ imgt, const u16* __restrict__ qwb,
        const float* __restrict__ qb, float* __restrict__ attn) {
    int b = blockIdx.y;
    int s0 = blockIdx.x * 256 + (threadIdx.x >> 6) * 64;
    int ln = threadIdx.x & 63;
    int col = ln & 15, g = ln >> 4;
    bf16x8 af[10][2];
    const u16* qa = qwb + (size_t)b * 10 * 2 * 512;
#pragma unroll
    for (int kk = 0; kk < 10; ++kk)
#pragma unroll
        for (int mf = 0; mf < 2; ++mf)
            af[kk][mf] = *reinterpret_cast<const bf16x8*>(qa + (((kk << 1) + mf) << 9) + (ln << 3));
    f32x4 acc[2][4];
#pragma unroll
    for (int mf = 0; mf < 2; ++mf)
#pragma unroll
        for (int nf = 0; nf < 4; ++nf) acc[mf][nf] = (f32x4){0.f, 0.f, 0.f, 0.f};
    const u16* xb = imgt + (size_t)b * NS * NC;
#pragma unroll
    for (int kk = 0; kk < 10; ++kk) {
#pragma unroll
        for (int nf = 0; nf < 4; ++nf) {
            bf16x8 bf = *reinterpret_cast<const bf16x8*>(
                xb + (size_t)(s0 + nf * 16 + col) * NC + kk * 32 + (g << 3));
#pragma unroll
            for (int mf = 0; mf < 2; ++mf)
                acc[mf][nf] = __builtin_amdgcn_mfma_f32_16x16x32_bf16(
                    af[kk][mf], bf, acc[mf][nf], 0, 0, 0);
        }
    }
#pragma unroll
    for (int mf = 0; mf < 2; ++mf)
#pragma unroll
        for (int nf = 0; nf < 4; ++nf)
#pragma unroll
            for (int r = 0; r < 4; ++r) {
                int row = mf * 16 + g * 4 + r;
                attn[((size_t)(b * NR + row) << 14) + s0 + nf * 16 + col] =
                    (acc[mf][nf][r] + qb[b * NR + row]) * SCALE;
            }
}

// ---------- 4a. softmax partial ----------
__global__ __launch_bounds__(256) void smax_part_kernel(const float* __restrict__ attn,
        float* __restrict__ pm, float* __restrict__ pl) {
    int row = blockIdx.x, kc = blockIdx.y;
    const float* rp = attn + ((size_t)row << 14) + kc * 2048;
    __shared__ float red[8];
    int t4 = threadIdx.x * 4;
    float4 v0 = *reinterpret_cast<const float4*>(rp + t4);
    float4 v1 = *reinterpret_cast<const float4*>(rp + t4 + 1024);
    float m = fmaxf(fmaxf(fmaxf(v0.x, v0.y), fmaxf(v0.z, v0.w)),
                    fmaxf(fmaxf(v1.x, v1.y), fmaxf(v1.z, v1.w)));
    m = blk_max(m, red);
    float s = expf(v0.x - m) + expf(v0.y - m) + expf(v0.z - m) + expf(v0.w - m)
            + expf(v1.x - m) + expf(v1.y - m) + expf(v1.z - m) + expf(v1.w - m);
    s = blk_sum(s, red);
    if (threadIdx.x == 0) { pm[row * 8 + kc] = m; pl[row * 8 + kc] = s; }
}

// ---------- 4b. combine chunk stats ----------
__global__ __launch_bounds__(128) void smax_comb_kernel(const float* __restrict__ pm,
        const float* __restrict__ pl, float* __restrict__ gm, float* __restrict__ gli) {
    int row = threadIdx.x;
    float M = -1e30f;
#pragma unroll
    for (int k = 0; k < 8; ++k) M = fmaxf(M, pm[row * 8 + k]);
    float L = 0.f;
#pragma unroll
    for (int k = 0; k < 8; ++k) L += pl[row * 8 + k] * expf(pm[row * 8 + k] - M);
    gm[row] = M; gli[row] = 1.f / L;
}

// ---------- 4c. softmax finalize: f32 (f32 mode) or bf16 (bf16 mode) ----------
__global__ __launch_bounds__(256) void smax_fin_kernel(const int* __restrict__ flag,
        float* __restrict__ attn, const float* __restrict__ gm, const float* __restrict__ gli,
        u16* __restrict__ attnb) {
    int mode = *flag;
    int row = blockIdx.x, kc = blockIdx.y;
    size_t base = ((size_t)row << 14) + kc * 2048;
    float M = gm[row], LI = gli[row];
    int t4 = threadIdx.x * 4;
#pragma unroll
    for (int h = 0; h < 2; ++h) {
        size_t i = base + t4 + h * 1024;
        float4 v = *reinterpret_cast<const float4*>(attn + i);
        v.x = expf(v.x - M) * LI; v.y = expf(v.y - M) * LI;
        v.z = expf(v.z - M) * LI; v.w = expf(v.w - M) * LI;
        if (mode == 1) {
            *reinterpret_cast<float4*>(attn + i) = v;
        } else {
            ushort4 bv; bv.x = fbu(v.x); bv.y = fbu(v.y); bv.z = fbu(v.z); bv.w = fbu(v.w);
            *reinterpret_cast<ushort4*>(attnb + i) = bv;
        }
    }
}

// ---------- 5A (bf16 mode). MFMA y ----------
__global__ __launch_bounds__(256) void ymm_kernel(const int* __restrict__ flag,
        const u16* __restrict__ attnb, const void* __restrict__ img, float* __restrict__ yp) {
    if (*flag != 0) return;
    int kc = blockIdx.x, ct = blockIdx.y, b = blockIdx.z;
    int wv = threadIdx.x >> 6, ln = threadIdx.x & 63;
    int col = ln & 15, g = ln >> 4;
    int s0 = kc * YCS;
    const u16* imgB = (const u16*)img;
    const u16* ap0 = attnb + (((size_t)b * 32 + col) << 14) + s0 + (g << 3);
    const u16* bp  = imgB + (((size_t)(b * NC + ct * 64 + wv * 16 + col)) << 14) + s0 + (g << 3);
    f32x4 acc[2];
    acc[0] = (f32x4){0.f, 0.f, 0.f, 0.f};
    acc[1] = (f32x4){0.f, 0.f, 0.f, 0.f};
#pragma unroll
    for (int ks = 0; ks < YCS / 32; ++ks) {
        bf16x8 bf = *reinterpret_cast<const bf16x8*>(bp + ks * 32);
        bf16x8 a0 = *reinterpret_cast<const bf16x8*>(ap0 + ks * 32);
        bf16x8 a1 = *reinterpret_cast<const bf16x8*>(ap0 + (16 << 14) + ks * 32);
        acc[0] = __builtin_amdgcn_mfma_f32_16x16x32_bf16(a0, bf, acc[0], 0, 0, 0);
        acc[1] = __builtin_amdgcn_mfma_f32_16x16x32_bf16(a1, bf, acc[1], 0, 0, 0);
    }
    int c = ct * 64 + wv * 16 + col;
#pragma unroll
    for (int mf = 0; mf < 2; ++mf)
#pragma unroll
        for (int r = 0; r < 4; ++r) {
            int row = b * 32 + mf * 16 + g * 4 + r;
            yp[((size_t)kc * NB * NR + row) * NC + c] = acc[mf][r];
        }
}

// ---------- 5B (f32 mode). VALU y ----------
template <typename T>
__global__ __launch_bounds__(256) void y_kernel(const int* __restrict__ flag,
        const float* __restrict__ attn, const void* __restrict__ img, float* __restrict__ yp) {
    if (*flag != ModeOf<T>::v) return;
    int row = blockIdx.x;
    int ks  = blockIdx.y;
    int b = row >> 5;
    int wv = threadIdx.x >> 6, ln = threadIdx.x & 63;
    const float* ar = attn + ((size_t)row << 14) + ks * YCH;
    size_t xb = (size_t)b * NC * NS + ks * YCH;
    float* yout = yp + ((size_t)ks * NB * NR + row) * NC;
    for (int c = wv; c < NC; c += 4) {
        size_t xr = xb + ((size_t)c << 14);
        float p = 0.f;
#pragma unroll
        for (int it = 0; it < YCH / 512; ++it)
            p += dot8f((const float*)img, xr, ar, it * 512 + ln * 8);
#pragma unroll
        for (int o = 32; o > 0; o >>= 1) p += __shfl_down(p, o, 64);
        if (ln == 0) yout[c] = p;
    }
}

// ---------- 5b. y reduce over K-chunks ----------
__global__ __launch_bounds__(256) void yred_kernel(const int* __restrict__ flag, int mode, int nk,
        const float* __restrict__ yp, float* __restrict__ y) {
    if (*flag != mode) return;
    int i = blockIdx.x * 256 + threadIdx.x;
    if (i >= NB * NR * NC) return;
    float s = 0.f;
    for (int k = 0; k < nk; ++k) s += yp[(size_t)k * NB * NR * NC + i];
    y[i] = s;
}

// ---------- 6. o = Wv-contraction of y; o2 = LN(o @ Wo^T + bo) ----------
template <typename T>
__global__ __launch_bounds__(256) void o_kernel(const int* __restrict__ flag,
        const float* __restrict__ y, const void* __restrict__ Wv, const void* __restrict__ bv,
        const void* __restrict__ Wo, const void* __restrict__ bo,
        const void* __restrict__ lnw, const void* __restrict__ lnb, float* __restrict__ o2) {
    if (*flag != ModeOf<T>::v) return;
    int b = blockIdx.x, tid = threadIdx.x;
    __shared__ float yl[NR * NC];
    __shared__ float ol[NQD];
    __shared__ float red[8];
    for (int i = tid; i < NR * NC; i += 256) yl[i] = y[(size_t)b * NR * NC + i];
    __syncthreads();
#pragma unroll
    for (int k = 0; k < 5; ++k) {
        int i = tid + k * 256;
        int h = i / 160, rem = i - h * 160;
        int d = rem >> 2, t = rem & 3;
        int wr = h * NHD + d, r = h * NTOK + t;
        float a = ld<T>(bv, wr);
        size_t wvr = (size_t)wr * NC;
        const float* yr = yl + r * NC;
        for (int c = 0; c < NC; ++c) a += ld<T>(Wv, wvr + c) * yr[c];
        ol[i] = a;
    }
    __syncthreads();
    for (int j = tid; j < NC; j += 256) {
        float a = ld<T>(bo, j);
        size_t wor = (size_t)j * NQD;
        for (int i = 0; i < NQD; ++i) a += ld<T>(Wo, wor + i) * ol[i];
        yl[j] = a;
    }
    __syncthreads();
    float s1 = 0.f, s2 = 0.f;
    for (int j = tid; j < NC; j += 256) { float v = yl[j]; s1 += v; s2 += v * v; }
    s1 = blk_sum(s1, red);
    s2 = blk_sum(s2, red);
    float mu = s1 / (float)NC;
    float var = fmaxf(s2 / (float)NC - mu * mu, 0.f);
    float rs = rsqrtf(var + EPSV);
    for (int j = tid; j < NC; j += 256)
        o2[(size_t)b * NC + j] = (yl[j] - mu) * rs * ld<T>(lnw, j) + ld<T>(lnb, j);
}

// ---------- 7. P broadcast taps ----------
template <typename T>
__global__ __launch_bounds__(256) void p_kernel(const int* __restrict__ flag,
        const float* __restrict__ o2, const void* __restrict__ Wf1, float* __restrict__ P) {
    if (*flag != ModeOf<T>::v) return;
    int o = blockIdx.x, b = blockIdx.y;
    int tid = threadIdx.x, wv = tid >> 6, ln = tid & 63;
    __shared__ float red[4 * 27];
    __shared__ float taps[27];
    float acc[27];
#pragma unroll
    for (int k = 0; k < 27; ++k) acc[k] = 0.f;
    for (int c = tid; c < NC; c += 256) {
        float oc = o2[(size_t)b * NC + c];
        size_t wp = ((size_t)o * 640 + 320 + c) * 27;
#pragma unroll
        for (int k = 0; k < 27; ++k) acc[k] += oc * ld<T>(Wf1, wp + k);
    }
#pragma unroll
    for (int k = 0; k < 27; ++k) {
        float v = acc[k];
#pragma unroll
        for (int off = 32; off > 0; off >>= 1) v += __shfl_down(v, off, 64);
        if (ln == 0) red[wv * 27 + k] = v;
    }
    __syncthreads();
    if (tid < 27) taps[tid] = red[tid] + red[27 + tid] + red[54 + tid] + red[81 + tid];
    __syncthreads();
    if (tid < 27) {
        int pd = tid / 9, ph = (tid / 3) % 3, pw = tid % 3;
        float s = 0.f;
        for (int kd = 0; kd < 3; ++kd) {
            if ((pd == 0 && kd == 0) || (pd == 2 && kd == 2)) continue;
            for (int kh = 0; kh < 3; ++kh) {
                if ((ph == 0 && kh == 0) || (ph == 2 && kh == 2)) continue;
                for (int kw = 0; kw < 3; ++kw) {
                    if ((pw == 0 && kw == 0) || (pw == 2 && kw == 2)) continue;
                    s += taps[kd * 9 + kh * 3 + kw];
                }
            }
        }
        P[(size_t)(b * NC + o) * 27 + tid] = s;
    }
}

// ---------- 8a. channel-last transpose ----------
template <typename T>
__global__ __launch_bounds__(256) void imgt_kernel(const int* __restrict__ flag,
        const void* __restrict__ img, u16* __restrict__ outT) {
    if (*flag != ModeOf<T>::v) return;
    int b = blockIdx.z, c0 = blockIdx.y << 5, s0 = blockIdx.x << 5;
    int r = threadIdx.x >> 3, c4 = (threadIdx.x & 7) << 2;
    __shared__ float tile[32][33];
#pragma unroll
    for (int j = 0; j < 4; ++j)
        tile[r][c4 + j] = ld<T>(img, ((size_t)(b * NC + c0 + r) << 14) + s0 + c4 + j);
    __syncthreads();
    u16* op = outT + ((size_t)b * NS + s0 + r) * NC + c0 + c4;
#pragma unroll
    for (int j = 0; j < 4; ++j) op[j] = fbu(tile[c4 + j][r]);
}

// ---------- 8b. weight pre-pack ----------
template <typename TW>
__global__ __launch_bounds__(256) void pack_kernel(const int* __restrict__ flag,
        const void* __restrict__ wgt, const void* __restrict__ bias,
        u16* __restrict__ wpack, float* __restrict__ biasf, int wic) {
    if (*flag != ModeOf<TW>::v) return;
    int gid = blockIdx.x * 256 + threadIdx.x;
    if (gid < NC) biasf[gid] = ld<TW>(bias, gid);
    int lane = gid & 63;
    int rest = gid >> 6;
    int obg = rest % 20;  rest /= 20;
    int t = rest % 27;    int cs = rest / 27;
    int o  = (obg << 4) + (lane & 15);
    int c0 = (cs << 5) + ((lane >> 4) << 3);
    u16* dst = wpack + (size_t)gid * 8;
#pragma unroll
    for (int j = 0; j < 8; ++j)
        dst[j] = fbu(ld<TW>(wgt, ((size_t)o * wic + c0 + j) * 27 + t));
}

// ---------- 8c. MFMA implicit-GEMM conv (round-3 measured-optimal config) ----------
__global__ __launch_bounds__(256, 3) void convmm_kernel(
        const u16* __restrict__ inT, const u16* __restrict__ wpack,
        const float* __restrict__ biasf, const float* __restrict__ Pp,
        u16* __restrict__ out) {
    int d0 = (blockIdx.x >> 3) << 1;   // 8 d-tiles of 2
    int h0 = (blockIdx.x & 7) << 2;    // 8 h-tiles of 4
    int ob = blockIdx.y;               // o-tile (64 o's)
    int b  = blockIdx.z;
    int tid = threadIdx.x;
    int wv = tid >> 6, ln = tid & 63;
    int col = ln & 15, g = ln >> 4;

    __shared__ __align__(16) u16 lin[NPIX * CSL];   // 52224 B

    {
        float4 z = {0.f, 0.f, 0.f, 0.f};
        float4* lp = reinterpret_cast<float4*>(lin);
        for (int i = tid; i < NPIX * CSL / 8; i += 256) lp[i] = z;
    }
    __syncthreads();

    f32x4 acc[4][4];
#pragma unroll
    for (int mi = 0; mi < 4; ++mi)
#pragma unroll
        for (int ni = 0; ni < 4; ++ni) acc[mi][ni] = (f32x4){0.f, 0.f, 0.f, 0.f};

    int pix0[4];
#pragma unroll
    for (int ni = 0; ni < 4; ++ni) {
        int nb = (wv << 2) + ni;
        int r2 = nb >> 1;
        int ddo = r2 >> 2, hho = r2 & 3;
        pix0[ni] = (ddo * HALO_H + hho) * PIXW + ((nb & 1) << 4) + col;
    }

    size_t inb = (size_t)b * NS * NC;

    for (int cs = 0; cs < NSL; ++cs) {
        for (int k = wv; k < 48; k += 4) {
            int hf = k & 1, rr = k >> 1;
            int dd = rr / HALO_H, hh = rr - dd * HALO_H;
            int dg = d0 + dd - 1, hg = h0 + hh - 1;
            if ((unsigned)dg < ND && (unsigned)hg < NH) {
                int pixbase = (dd * HALO_H + hh) * PIXW + 1 + (hf << 4);
                int p = pixbase + (ln >> 2);
                int wpos = (hf << 4) + (ln >> 2);
                int cg = (ln & 3) ^ swz4(p);
                const u16* src = inT + inb + ((size_t)(dg << 10) + (hg << 5) + wpos) * NC
                                 + (cs << 5) + (cg << 3);
                __builtin_amdgcn_global_load_lds(
                    (const __attribute__((address_space(1))) unsigned int*)src,
                    (__attribute__((address_space(3))) unsigned int*)(lin + pixbase * CSL),
                    16, 0, 0);
            }
        }
        __syncthreads();

        const u16* wp = wpack + (size_t)cs * 27 * 20 * 512;
#pragma unroll
        for (int t = 0; t < 27; ++t) {
            const int kd = t / 9, kh = (t / 3) % 3, kw = t % 3;
            bf16x8 af[4];
#pragma unroll
            for (int mi = 0; mi < 4; ++mi)
                af[mi] = *reinterpret_cast<const bf16x8*>(
                    wp + ((size_t)(t * 20 + (ob << 2) + mi) << 9) + (ln << 3));
            bf16x8 bfr[4];
#pragma unroll
            for (int ni = 0; ni < 4; ++ni) {
                int p = pix0[ni] + (kd * HALO_H + kh) * PIXW + kw;
                bfr[ni] = *reinterpret_cast<const bf16x8*>(
                    lin + p * CSL + ((g ^ swz4(p)) << 3));
            }
#pragma unroll
            for (int mi = 0; mi < 4; ++mi)
#pragma unroll
                for (int ni = 0; ni < 4; ++ni)
                    acc[mi][ni] = __builtin_amdgcn_mfma_f32_16x16x32_bf16(
                        af[mi], bfr[ni], acc[mi][ni], 0, 0, 0);
        }
        __syncthreads();
    }

#pragma unroll
    for (int ni = 0; ni < 4; ++ni) {
        int nb = (wv << 2) + ni;
        int r2 = nb >> 1;
        int d = d0 + (r2 >> 2);
        int h = h0 + (r2 & 3);
        int w = ((nb & 1) << 4) + col;
        int pd = (d == 0) ? 0 : ((d == ND - 1) ? 2 : 1);
        int ph = (h == 0) ? 0 : ((h == NH - 1) ? 2 : 1);
        int pw = (w == 0) ? 0 : ((w == NW - 1) ? 2 : 1);
        size_t sidx = ((size_t)d << 10) + (h << 5) + w;
#pragma unroll
        for (int mi = 0; mi < 4; ++mi) {
#pragma unroll
            for (int r = 0; r < 4; ++r) {
                int o = (ob << 6) + (mi << 4) + (g << 2) + r;
                float v = acc[mi][ni][r] + biasf[o];
                if (Pp) v += Pp[(size_t)(b * NC + o) * 27 + pd * 9 + ph * 3 + pw];
                out[((size_t)(b * NC + o) << 14) + sidx] = fbu(v);
            }
        }
    }
}

// ---------- 9. per-(b,o) mean / rstd over S (bf16 input, 16B loads) ----------
__global__ __launch_bounds__(256) void stats_kernel(const u16* __restrict__ raw, float* __restrict__ mean,
                                                    float* __restrict__ rstd) {
    int bo = blockIdx.x;
    const u16* base = raw + ((size_t)bo << 14);
    __shared__ float red[8];
    float s1 = 0.f, s2 = 0.f;
    for (int s0 = threadIdx.x * 8; s0 < NS; s0 += 2048) {
        uint4 v = *reinterpret_cast<const uint4*>(base + s0);
        float x0 = bfu(v.x & 0xffff), x1 = bfu(v.x >> 16);
        float x2 = bfu(v.y & 0xffff), x3 = bfu(v.y >> 16);
        float x4 = bfu(v.z & 0xffff), x5 = bfu(v.z >> 16);
        float x6 = bfu(v.w & 0xffff), x7 = bfu(v.w >> 16);
        s1 += ((x0 + x1) + (x2 + x3)) + ((x4 + x5) + (x6 + x7));
        s2 += ((x0*x0 + x1*x1) + (x2*x2 + x3*x3)) + ((x4*x4 + x5*x5) + (x6*x6 + x7*x7));
    }
    s1 = blk_sum(s1, red);
    s2 = blk_sum(s2, red);
    if (threadIdx.x == 0) {
        float mu = s1 / (float)NS;
        float var = fmaxf(s2 / (float)NS - mu * mu, 0.f);
        mean[bo] = mu;
        rstd[bo] = rsqrtf(var + EPSV);
    }
}

// ---------- 10. h1 = gelu(instnorm(raw1)) -> channel-last bf16 ----------
__global__ __launch_bounds__(256) void norm1t_kernel(const u16* __restrict__ raw,
        const float* __restrict__ mean, const float* __restrict__ rstd, u16* __restrict__ h1t) {
    int b = blockIdx.z, c0 = blockIdx.y << 5, s0 = blockIdx.x << 5;
    int r = threadIdx.x >> 3, c4 = (threadIdx.x & 7) << 2;
    __shared__ float tile[32][33];
    int bo = b * NC + c0 + r;
    float mu = mean[bo], rs = rstd[bo];
    const u16* rp = raw + ((size_t)bo << 14) + s0 + c4;
#pragma unroll
    for (int j = 0; j < 4; ++j) {
        float xn = (bfu(rp[j]) - mu) * rs;
        tile[r][c4 + j] = 0.5f * xn * (1.f + erff(xn * 0.70710678118654752f));
    }
    __syncthreads();
    u16* op = h1t + ((size_t)b * NS + s0 + r) * NC + c0 + c4;
#pragma unroll
    for (int j = 0; j < 4; ++j) op[j] = fbu(tile[c4 + j][r]);
}

// ---------- 11. out = instnorm(raw2) + img, 4 elems/thread ----------
template <typename T>
__global__ __launch_bounds__(256) void final_kernel(const int* __restrict__ flag,
        const u16* __restrict__ raw, const float* __restrict__ mean, const float* __restrict__ rstd,
        const void* __restrict__ img, void* __restrict__ outp) {
    if (*flag != ModeOf<T>::v) return;
    int idx = (blockIdx.x * 256 + threadIdx.x) * 4;
    if (idx >= OUT_N) return;
    int bo = idx >> 14;
    float mu = mean[bo], rs = rstd[bo];
    ushort4 rv = *reinterpret_cast<const ushort4*>(raw + idx);
    float r0 = (bfu(rv.x) - mu) * rs;
    float r1 = (bfu(rv.y) - mu) * rs;
    float r2 = (bfu(rv.z) - mu) * rs;
    float r3 = (bfu(rv.w) - mu) * rs;
    if (ModeOf<T>::v == 0) {
        ushort4 iv = *reinterpret_cast<const ushort4*>((const u16*)img + idx);
        ushort4 ov;
        ov.x = fbu(r0 + bfu(iv.x)); ov.y = fbu(r1 + bfu(iv.y));
        ov.z = fbu(r2 + bfu(iv.z)); ov.w = fbu(r3 + bfu(iv.w));
        *reinterpret_cast<ushort4*>((u16*)outp + idx) = ov;
    } else {
        float4 iv = *reinterpret_cast<const float4*>((const float*)img + idx);
        float4 ov = make_float4(r0 + iv.x, r1 + iv.y, r2 + iv.z, r3 + iv.w);
        *reinterpret_cast<float4*>((float*)outp + idx) = ov;
    }
}

extern "C" void kernel_launch(void* const* d_in, const int* in_sizes, int n_in,
                              void* d_out, int out_size, void* d_ws, size_t ws_size,
                              hipStream_t stream) {
    const void* IMG  = d_in[0];
    const void* CLI  = d_in[1];
    const void* WQ   = d_in[2];
    const void* BQ   = d_in[3];
    const void* LNQW = d_in[4];
    const void* LNQB = d_in[5];
    const void* WK   = d_in[6];
    const void* BK   = d_in[7];
    const void* WV   = d_in[8];
    const void* BV   = d_in[9];
    const void* WO   = d_in[10];
    const void* BO   = d_in[11];
    const void* LNOW = d_in[12];
    const void* LNOB = d_in[13];
    const void* WF1  = d_in[14];
    const void* BF1  = d_in[15];
    const void* WF2  = d_in[16];
    const void* BF2  = d_in[17];

    char* ws = (char*)d_ws;
    size_t off = 0;
    auto alloc = [&](size_t bytes) { void* p = ws + off; off += (bytes + 255) & ~(size_t)255; return p; };
    int*   FLAG  = (int*)  alloc(256);
    u16*   RAW   = (u16*)  alloc((size_t)OUT_N * 2);         // 41.9 MB
    float* Qf    = (float*)alloc((size_t)NB * NQD * 4);
    float* QW    = (float*)alloc((size_t)NB * NR * NC * 4);
    float* QB    = (float*)alloc((size_t)NB * NR * 4);
    u16*   QWB   = (u16*)  alloc((size_t)NB * 10 * 2 * 512 * 2);
    float* Yb    = (float*)alloc((size_t)NB * NR * NC * 4);
    float* O2    = (float*)alloc((size_t)NB * NC * 4);
    float* PB    = (float*)alloc((size_t)NB * NC * 27 * 4);
    float* MEAN  = (float*)alloc((size_t)NB * NC * 4);
    float* RSTD  = (float*)alloc((size_t)NB * NC * 4);
    float* PM    = (float*)alloc((size_t)NB * NR * 8 * 4);
    float* PL    = (float*)alloc((size_t)NB * NR * 8 * 4);
    float* GM    = (float*)alloc((size_t)NB * NR * 4);
    float* GLI   = (float*)alloc((size_t)NB * NR * 4);
    u16*   WPACK = (u16*)  alloc((size_t)PACKN * 2);
    float* BIASF = (float*)alloc((size_t)NC * 4);
    // RAW region aliasing (RAW dead until convmm):
    float* YP    = (float*)RAW;                              // up to 5.25 MB (32 chunks)
    float* ATTN  = (float*)((char*)RAW + (16u << 20));       // 8.39 MB f32
    u16*   ATTNB = (u16*)  ((char*)RAW + (26u << 20));       // 4.2 MB bf16
    u16*   IMGT  = (u16*)d_out;
    u16*   H1    = (u16*)d_out;
    (void)ws_size; (void)n_in; (void)in_sizes; (void)out_size;

    detect_kernel<<<1, 64, 0, stream>>>((const u16*)LNQW, FLAG);

    imgt_kernel<u16>  <<<dim3(512, 10, NB), 256, 0, stream>>>(FLAG, IMG, IMGT);
    imgt_kernel<float><<<dim3(512, 10, NB), 256, 0, stream>>>(FLAG, IMG, IMGT);

    q_kernel<u16>  <<<NB, 256, 0, stream>>>(FLAG, CLI, WQ, BQ, LNQW, LNQB, Qf);
    q_kernel<float><<<NB, 256, 0, stream>>>(FLAG, CLI, WQ, BQ, LNQW, LNQB, Qf);

    int qwg = (NB * NR * NC + 255) / 256;
    qw_kernel<u16>  <<<qwg, 256, 0, stream>>>(FLAG, Qf, WK, BK, QW, QB, QWB);
    qw_kernel<float><<<qwg, 256, 0, stream>>>(FLAG, Qf, WK, BK, QW, QB, QWB);

    scores_mm_kernel<<<dim3(64, NB), 256, 0, stream>>>(IMGT, QWB, QB, ATTN);

    smax_part_kernel<<<dim3(NB * NR, 8), 256, 0, stream>>>(ATTN, PM, PL);
    smax_comb_kernel<<<1, 128, 0, stream>>>(PM, PL, GM, GLI);
    smax_fin_kernel<<<dim3(NB * NR, 8), 256, 0, stream>>>(FLAG, ATTN, GM, GLI, ATTNB);

    ymm_kernel<<<dim3(YKC, 5, NB), 256, 0, stream>>>(FLAG, ATTNB, IMG, YP);
    y_kernel<float><<<dim3(NB * NR, YKS), 256, 0, stream>>>(FLAG, ATTN, IMG, YP);

    int yrg = (NB * NR * NC + 255) / 256;
    yred_kernel<<<yrg, 256, 0, stream>>>(FLAG, 0, YKC, YP, Yb);
    yred_kernel<<<yrg, 256, 0, stream>>>(FLAG, 1, YKS, YP, Yb);

    o_kernel<u16>  <<<NB, 256, 0, stream>>>(FLAG, Yb, WV, BV, WO, BO, LNOW, LNOB, O2);
    o_kernel<float><<<NB, 256, 0, stream>>>(FLAG, Yb, WV, BV, WO, BO, LNOW, LNOB, O2);

    p_kernel<u16>  <<<dim3(NC, NB), 256, 0, stream>>>(FLAG, O2, WF1, PB);
    p_kernel<float><<<dim3(NC, NB), 256, 0, stream>>>(FLAG, O2, WF1, PB);

    int pkg = (PACKN / 8 + 255) / 256;
    pack_kernel<u16>  <<<pkg, 256, 0, stream>>>(FLAG, WF1, BF1, WPACK, BIASF, 640);
    pack_kernel<float><<<pkg, 256, 0, stream>>>(FLAG, WF1, BF1, WPACK, BIASF, 640);

    convmm_kernel<<<dim3(64, 5, NB), 256, 0, stream>>>(IMGT, WPACK, BIASF, PB, RAW);

    stats_kernel<<<NB * NC, 256, 0, stream>>>(RAW, MEAN, RSTD);
    norm1t_kernel<<<dim3(512, 10, NB), 256, 0, stream>>>(RAW, MEAN, RSTD, H1);

    pack_kernel<u16>  <<<pkg, 256, 0, stream>>>(FLAG, WF2, BF2, WPACK, BIASF, 320);
    pack_kernel<float><<<pkg, 256, 0, stream>>>(FLAG, WF2, BF2, WPACK, BIASF, 320);

    convmm_kernel<<<dim3(64, 5, NB), 256, 0, stream>>>(H1, WPACK, BIASF, nullptr, RAW);

    stats_kernel<<<NB * NC, 256, 0, stream>>>(RAW, MEAN, RSTD);

    final_kernel<u16>  <<<(OUT_N / 4 + 255) / 256, 256, 0, stream>>>(FLAG, RAW, MEAN, RSTD, IMG, d_out);
    final_kernel<float><<<(OUT_N / 4 + 255) / 256, 256, 0, stream>>>(FLAG, RAW, MEAN, RSTD, IMG, d_out);
}